// Round 1
// baseline (1172.033 us; speedup 1.0000x reference)
//
#include <hip/hip_runtime.h>

#define U_CNT 100000
#define I_CNT 50000
#define N_CNT 150000
#define D_CNT 64
#define NNZ_CNT 1000000

#define OFF_ITEM   6400000LL
#define OFF_STACK  9600000LL
#define OFF_PATH   48000000LL

#define RPB   64      // rows per bucket (LDS acc = 64*64*4 = 16 KB -> 8 blocks/CU)
#define NBUK  2344    // ceil(150000/64)
#define EPB   16384   // edges per block in build kernels
#define NBLD  62      // ceil(NNZ/EPB)

// ---------------- bucket-CSR build ----------------

__global__ void bzero_k(int* __restrict__ cnt) {
    int i = blockIdx.x * blockDim.x + threadIdx.x;
    if (i < 2 * NBUK) cnt[i] = 0;
}

// LDS-privatized bucket histogram; one coalesced flush per block.
__global__ __launch_bounds__(256) void bhist_k(const int* __restrict__ arows,
                                               const int* __restrict__ rrows,
                                               int* __restrict__ cnt) {
    __shared__ int h[NBUK];
    for (int i = threadIdx.x; i < NBUK; i += 256) h[i] = 0;
    __syncthreads();
    const int* rows = blockIdx.y ? rrows : arows;
    int base = blockIdx.x * EPB;
    int end = min(base + EPB, NNZ_CNT);
    for (int i = base + threadIdx.x; i < end; i += 256)
        atomicAdd(&h[rows[i] >> 6], 1);
    __syncthreads();
    int* c = cnt + blockIdx.y * NBUK;
    for (int i = threadIdx.x; i < NBUK; i += 256) {
        int v = h[i];
        if (v) atomicAdd(&c[i], v);
    }
}

// exclusive scan of NBUK counts per array; one block per array (blockIdx.x).
__global__ __launch_bounds__(1024) void bscan_k(const int* __restrict__ cnt,
                                                int* __restrict__ off,
                                                int* __restrict__ cur) {
    __shared__ int s[1024];
    const int* c = cnt + blockIdx.x * NBUK;
    int t = threadIdx.x;
    int v[3];
    int run = 0;
    int base = t * 3;
    #pragma unroll
    for (int k = 0; k < 3; ++k) {
        v[k] = (base + k < NBUK) ? c[base + k] : 0;
        run += v[k];
    }
    s[t] = run;
    __syncthreads();
    for (int d = 1; d < 1024; d <<= 1) {
        int a = (t >= d) ? s[t - d] : 0;
        __syncthreads();
        s[t] += a;
        __syncthreads();
    }
    int pre = (t > 0) ? s[t - 1] : 0;
    int* o = off + blockIdx.x * NBUK;
    int* u = cur + blockIdx.x * NBUK;
    #pragma unroll
    for (int k = 0; k < 3; ++k) {
        if (base + k < NBUK) { o[base + k] = pre; u[base + k] = pre; }
        pre += v[k];
    }
}

// scatter edges into bucket-grouped order; per-(block,bucket) chunk reservation
// so global atomics drop ~7x and same-bucket writes from a block are contiguous.
__global__ __launch_bounds__(256) void bscat_k(
    const int* __restrict__ arows, const int* __restrict__ acols, const float* __restrict__ avals,
    const int* __restrict__ rrows, const int* __restrict__ rcols, const float* __restrict__ rvals,
    int* __restrict__ cur, int2* __restrict__ ed) {
    __shared__ int h[NBUK];
    const int*   rows = blockIdx.y ? rrows : arows;
    const int*   cols = blockIdx.y ? rcols : acols;
    const float* vals = blockIdx.y ? rvals : avals;
    int*  c = cur + blockIdx.y * NBUK;
    int2* e = ed + (size_t)blockIdx.y * NNZ_CNT;
    for (int i = threadIdx.x; i < NBUK; i += 256) h[i] = 0;
    __syncthreads();
    int base = blockIdx.x * EPB;
    int end = min(base + EPB, NNZ_CNT);
    for (int i = base + threadIdx.x; i < end; i += 256)
        atomicAdd(&h[rows[i] >> 6], 1);
    __syncthreads();
    for (int i = threadIdx.x; i < NBUK; i += 256) {
        int n = h[i];
        h[i] = n ? atomicAdd(&c[i], n) : 0;   // h[b] becomes running global cursor
    }
    __syncthreads();
    for (int i = base + threadIdx.x; i < end; i += 256) {
        int r = rows[i];
        int pos = atomicAdd(&h[r >> 6], 1);
        e[pos] = make_int2(((r & 63) << 18) | cols[i], __float_as_int(vals[i]));
    }
}

// block per bucket: 4 waves stream the bucket's edges (coalesced batches of 64),
// gather emb rows, accumulate into LDS acc[64][64] via ds_add_f32.
__global__ __launch_bounds__(256) void bspmm_k(
    const int* __restrict__ off, const int* __restrict__ cnt,
    const int2* __restrict__ ed,
    const float* __restrict__ user_emb, const float* __restrict__ item_emb,
    float* __restrict__ out) {
    __shared__ float acc[RPB * D_CNT];  // 16 KB
    int which = blockIdx.y;
    int b = blockIdx.x;
    const int2* e = ed + (size_t)which * NNZ_CNT;
    int o = off[which * NBUK + b];
    int c = cnt[which * NBUK + b];
    int wid = threadIdx.x >> 6, lane = threadIdx.x & 63;
    for (int i = threadIdx.x; i < RPB * D_CNT; i += 256) acc[i] = 0.f;
    __syncthreads();
    for (int base = wid * 64; base < c; base += 256) {
        int m = min(64, c - base);
        int2 ev = make_int2(0, 0);
        if (lane < m) ev = e[o + base + lane];
        for (int j = 0; j < m; ++j) {
            int   pack = __shfl(ev.x, j);
            float v    = __int_as_float(__shfl(ev.y, j));
            int col = pack & 0x3FFFF;
            int rl  = pack >> 18;
            const float* src = (col < U_CNT) ? (user_emb + (size_t)col * D_CNT)
                                             : (item_emb + (size_t)(col - U_CNT) * D_CNT);
            // acc[rl*64+lane]: 2-way bank alias for a wave64 -> conflict-free
            __hip_atomic_fetch_add(&acc[rl * D_CNT + lane], v * src[lane],
                                   __ATOMIC_RELAXED, __HIP_MEMORY_SCOPE_WORKGROUP);
        }
    }
    __syncthreads();
    // epilogue: each wave writes 16 rows (ego, acc x3, optional mean)
    for (int rl = wid * 16; rl < wid * 16 + 16; ++rl) {
        int row = b * RPB + rl;
        if (row >= N_CNT) break;
        float a = acc[rl * D_CNT + lane];
        const float* esrc = (row < U_CNT) ? (user_emb + (size_t)row * D_CNT)
                                          : (item_emb + (size_t)(row - U_CNT) * D_CNT);
        float eg = esrc[lane];
        long long rb = (which ? OFF_PATH : OFF_STACK) + (long long)row * 256;
        out[rb + lane]       = eg;
        out[rb + 64 + lane]  = a;
        out[rb + 128 + lane] = a;
        out[rb + 192 + lane] = a;
        if (which == 0) {
            float mv = 0.25f * eg + 0.75f * a;
            long long mb = (row < U_CNT) ? (long long)row * D_CNT
                                         : OFF_ITEM + (long long)(row - U_CNT) * D_CNT;
            out[mb + lane] = mv;
        }
    }
}

// ---------------- fallback atomic path (ws too small) ----------------

__global__ void zero_slot1_k(float* __restrict__ out) {
    int t = blockIdx.x * blockDim.x + threadIdx.x;
    if (t >= N_CNT * 16) return;
    int n = t >> 4, q = t & 15;
    long long off = (long long)n * 256 + 64 + (long long)q * 4;
    float4 z = make_float4(0.f, 0.f, 0.f, 0.f);
    *(float4*)(out + OFF_STACK + off) = z;
    *(float4*)(out + OFF_PATH  + off) = z;
}

__global__ void scatter_fb_k(const int* __restrict__ rows, const int* __restrict__ cols,
                             const float* __restrict__ vals,
                             const float* __restrict__ user_emb, const float* __restrict__ item_emb,
                             float* __restrict__ acc) {
    long long t = (long long)blockIdx.x * blockDim.x + threadIdx.x;
    int e = (int)(t >> 4);
    if (e >= NNZ_CNT) return;
    int q = (int)(t & 15);
    int r = rows[e];
    int c = cols[e];
    float v = vals[e];
    const float* src = (c < U_CNT) ? (user_emb + (long long)c * D_CNT)
                                   : (item_emb + (long long)(c - U_CNT) * D_CNT);
    float4 x = *(const float4*)(src + q * 4);
    float* dst = acc + (long long)r * 256 + q * 4;
    atomicAdd(dst + 0, v * x.x);
    atomicAdd(dst + 1, v * x.y);
    atomicAdd(dst + 2, v * x.z);
    atomicAdd(dst + 3, v * x.w);
}

__global__ void finalize_k(const float* __restrict__ user_emb,
                           const float* __restrict__ item_emb,
                           float* __restrict__ out) {
    int t = blockIdx.x * blockDim.x + threadIdx.x;
    if (t >= N_CNT * 16) return;
    int n = t >> 4, q = t & 15;
    const float* src = (n < U_CNT) ? (user_emb + (long long)n * D_CNT)
                                   : (item_emb + (long long)(n - U_CNT) * D_CNT);
    float4 e4 = *(const float4*)(src + q * 4);
    float* st = out + OFF_STACK + (long long)n * 256;
    float* pt = out + OFF_PATH  + (long long)n * 256;
    float4 a4 = *(const float4*)(st + 64 + q * 4);
    float4 r4 = *(const float4*)(pt + 64 + q * 4);
    float4 m4 = make_float4(0.25f * e4.x + 0.75f * a4.x, 0.25f * e4.y + 0.75f * a4.y,
                            0.25f * e4.z + 0.75f * a4.z, 0.25f * e4.w + 0.75f * a4.w);
    *(float4*)(st + q * 4)       = e4;
    *(float4*)(st + 128 + q * 4) = a4;
    *(float4*)(st + 192 + q * 4) = a4;
    *(float4*)(pt + q * 4)       = e4;
    *(float4*)(pt + 128 + q * 4) = r4;
    *(float4*)(pt + 192 + q * 4) = r4;
    float* md = (n < U_CNT) ? (out + (long long)n * D_CNT)
                            : (out + OFF_ITEM + (long long)(n - U_CNT) * D_CNT);
    *(float4*)(md + q * 4) = m4;
}

extern "C" void kernel_launch(void* const* d_in, const int* in_sizes, int n_in,
                              void* d_out, int out_size, void* d_ws, size_t ws_size,
                              hipStream_t stream) {
    const float* user_emb  = (const float*)d_in[0];
    const float* item_emb  = (const float*)d_in[1];
    const int*   adj_rows  = (const int*)d_in[2];
    const int*   adj_cols  = (const int*)d_in[3];
    const float* adj_vals  = (const float*)d_in[4];
    const int*   radj_rows = (const int*)d_in[5];
    const int*   radj_cols = (const int*)d_in[6];
    const float* radj_vals = (const float*)d_in[7];
    float* out = (float*)d_out;
    const int BLK = 256;

    // ws layout (ints): cnt[2*NBUK], off[2*NBUK], cur[2*NBUK], then int2 ed[2*NNZ]
    size_t need = (size_t)(6 * NBUK) * 4 + (size_t)2 * NNZ_CNT * 8;
    if (ws_size >= need) {
        int* cnt = (int*)d_ws;
        int* off = cnt + 2 * NBUK;
        int* cur = off + 2 * NBUK;
        int2* ed = (int2*)(cur + 2 * NBUK);

        bzero_k<<<(2 * NBUK + BLK - 1) / BLK, BLK, 0, stream>>>(cnt);
        bhist_k<<<dim3(NBLD, 2), 256, 0, stream>>>(adj_rows, radj_rows, cnt);
        bscan_k<<<2, 1024, 0, stream>>>(cnt, off, cur);
        bscat_k<<<dim3(NBLD, 2), 256, 0, stream>>>(adj_rows, adj_cols, adj_vals,
                                                   radj_rows, radj_cols, radj_vals,
                                                   cur, ed);
        bspmm_k<<<dim3(NBUK, 2), 256, 0, stream>>>(off, cnt, ed, user_emb, item_emb, out);
    } else {
        int zgrid = (N_CNT * 16 + BLK - 1) / BLK;
        int sgrid = (int)(((long long)NNZ_CNT * 16 + BLK - 1) / BLK);
        zero_slot1_k<<<zgrid, BLK, 0, stream>>>(out);
        scatter_fb_k<<<sgrid, BLK, 0, stream>>>(adj_rows, adj_cols, adj_vals,
                                                user_emb, item_emb, out + OFF_STACK + 64);
        scatter_fb_k<<<sgrid, BLK, 0, stream>>>(radj_rows, radj_cols, radj_vals,
                                                user_emb, item_emb, out + OFF_PATH + 64);
        finalize_k<<<zgrid, BLK, 0, stream>>>(user_emb, item_emb, out);
    }
}

// Round 2
// 1114.277 us; speedup vs baseline: 1.0518x; 1.0518x over previous
//
#include <hip/hip_runtime.h>

#define U_CNT 100000
#define I_CNT 50000
#define N_CNT 150000
#define D_CNT 64
#define NNZ_CNT 1000000

#define OFF_ITEM   6400000LL
#define OFF_STACK  9600000LL
#define OFF_PATH   48000000LL

#define RPB   64      // rows per bucket
#define ASTRIDE 65    // padded LDS row stride (floats) -> bank spread for ds_add
#define NBUK  2344    // ceil(150000/64)
#define EPB   16384   // edges per block in build kernels
#define NBLD  62      // ceil(NNZ/EPB)

// ---------------- bucket-CSR build ----------------

__global__ void bzero_k(int* __restrict__ cnt) {
    int i = blockIdx.x * blockDim.x + threadIdx.x;
    if (i < 2 * NBUK) cnt[i] = 0;
}

// LDS-privatized bucket histogram; one coalesced flush per block.
__global__ __launch_bounds__(256) void bhist_k(const int* __restrict__ arows,
                                               const int* __restrict__ rrows,
                                               int* __restrict__ cnt) {
    __shared__ int h[NBUK];
    for (int i = threadIdx.x; i < NBUK; i += 256) h[i] = 0;
    __syncthreads();
    const int* rows = blockIdx.y ? rrows : arows;
    int base = blockIdx.x * EPB;
    int end = min(base + EPB, NNZ_CNT);
    for (int i = base + threadIdx.x; i < end; i += 256)
        atomicAdd(&h[rows[i] >> 6], 1);
    __syncthreads();
    int* c = cnt + blockIdx.y * NBUK;
    for (int i = threadIdx.x; i < NBUK; i += 256) {
        int v = h[i];
        if (v) atomicAdd(&c[i], v);
    }
}

// exclusive scan of NBUK counts per array; one block per array (blockIdx.x).
__global__ __launch_bounds__(1024) void bscan_k(const int* __restrict__ cnt,
                                                int* __restrict__ off,
                                                int* __restrict__ cur) {
    __shared__ int s[1024];
    const int* c = cnt + blockIdx.x * NBUK;
    int t = threadIdx.x;
    int v[3];
    int run = 0;
    int base = t * 3;
    #pragma unroll
    for (int k = 0; k < 3; ++k) {
        v[k] = (base + k < NBUK) ? c[base + k] : 0;
        run += v[k];
    }
    s[t] = run;
    __syncthreads();
    for (int d = 1; d < 1024; d <<= 1) {
        int a = (t >= d) ? s[t - d] : 0;
        __syncthreads();
        s[t] += a;
        __syncthreads();
    }
    int pre = (t > 0) ? s[t - 1] : 0;
    int* o = off + blockIdx.x * NBUK;
    int* u = cur + blockIdx.x * NBUK;
    #pragma unroll
    for (int k = 0; k < 3; ++k) {
        if (base + k < NBUK) { o[base + k] = pre; u[base + k] = pre; }
        pre += v[k];
    }
}

// scatter edges into bucket-grouped order; per-(block,bucket) chunk reservation.
__global__ __launch_bounds__(256) void bscat_k(
    const int* __restrict__ arows, const int* __restrict__ acols, const float* __restrict__ avals,
    const int* __restrict__ rrows, const int* __restrict__ rcols, const float* __restrict__ rvals,
    int* __restrict__ cur, int2* __restrict__ ed) {
    __shared__ int h[NBUK];
    const int*   rows = blockIdx.y ? rrows : arows;
    const int*   cols = blockIdx.y ? rcols : acols;
    const float* vals = blockIdx.y ? rvals : avals;
    int*  c = cur + blockIdx.y * NBUK;
    int2* e = ed + (size_t)blockIdx.y * NNZ_CNT;
    for (int i = threadIdx.x; i < NBUK; i += 256) h[i] = 0;
    __syncthreads();
    int base = blockIdx.x * EPB;
    int end = min(base + EPB, NNZ_CNT);
    for (int i = base + threadIdx.x; i < end; i += 256)
        atomicAdd(&h[rows[i] >> 6], 1);
    __syncthreads();
    for (int i = threadIdx.x; i < NBUK; i += 256) {
        int n = h[i];
        h[i] = n ? atomicAdd(&c[i], n) : 0;   // h[b] becomes running global cursor
    }
    __syncthreads();
    for (int i = base + threadIdx.x; i < end; i += 256) {
        int r = rows[i];
        int pos = atomicAdd(&h[r >> 6], 1);
        e[pos] = make_int2(((r & 63) << 18) | cols[i], __float_as_int(vals[i]));
    }
}

// block per bucket: 256 threads = 16 edges x 16 float4-lanes per iteration.
// No LDS read in the loop -> gathers pipeline freely (the round-1 kernel
// serialized on the ds_bpermute that followed each ds_add in the LDS FIFO).
__global__ __launch_bounds__(256) void bspmm_k(
    const int* __restrict__ off, const int* __restrict__ cnt,
    const int2* __restrict__ ed,
    const float* __restrict__ user_emb, const float* __restrict__ item_emb,
    float* __restrict__ out) {
    __shared__ float acc[RPB * ASTRIDE];  // 16.64 KB -> 8 blocks/CU
    int which = blockIdx.y;
    int b = blockIdx.x;
    const int2* e = ed + (size_t)which * NNZ_CNT;
    int o = off[which * NBUK + b];
    int c = cnt[which * NBUK + b];
    int t = threadIdx.x;
    int eg = t >> 4;   // edge slot 0..15
    int q  = t & 15;   // float4 slot 0..15 (dim quarter)
    for (int i = t; i < RPB * ASTRIDE; i += 256) acc[i] = 0.f;
    __syncthreads();
    for (int base = 0; base < c; base += 16) {
        int idx = base + eg;
        if (idx < c) {
            int2 ev = e[o + idx];
            int pack = ev.x;
            float v = __int_as_float(ev.y);
            int col = pack & 0x3FFFF;
            int rl  = pack >> 18;
            const float* src = (col < U_CNT) ? (user_emb + (size_t)col * D_CNT)
                                             : (item_emb + (size_t)(col - U_CNT) * D_CNT);
            float4 x = *(const float4*)(src + q * 4);
            float* a = &acc[rl * ASTRIDE + q * 4];
            __hip_atomic_fetch_add(a + 0, v * x.x, __ATOMIC_RELAXED, __HIP_MEMORY_SCOPE_WORKGROUP);
            __hip_atomic_fetch_add(a + 1, v * x.y, __ATOMIC_RELAXED, __HIP_MEMORY_SCOPE_WORKGROUP);
            __hip_atomic_fetch_add(a + 2, v * x.z, __ATOMIC_RELAXED, __HIP_MEMORY_SCOPE_WORKGROUP);
            __hip_atomic_fetch_add(a + 3, v * x.w, __ATOMIC_RELAXED, __HIP_MEMORY_SCOPE_WORKGROUP);
        }
    }
    __syncthreads();
    // epilogue: each wave writes 16 rows (ego, acc x3, optional mean)
    int wid = t >> 6, lane = t & 63;
    for (int rl = wid * 16; rl < wid * 16 + 16; ++rl) {
        int row = b * RPB + rl;
        if (row >= N_CNT) break;
        float a = acc[rl * ASTRIDE + lane];
        const float* esrc = (row < U_CNT) ? (user_emb + (size_t)row * D_CNT)
                                          : (item_emb + (size_t)(row - U_CNT) * D_CNT);
        float eg2 = esrc[lane];
        long long rb = (which ? OFF_PATH : OFF_STACK) + (long long)row * 256;
        out[rb + lane]       = eg2;
        out[rb + 64 + lane]  = a;
        out[rb + 128 + lane] = a;
        out[rb + 192 + lane] = a;
        if (which == 0) {
            float mv = 0.25f * eg2 + 0.75f * a;
            long long mb = (row < U_CNT) ? (long long)row * D_CNT
                                         : OFF_ITEM + (long long)(row - U_CNT) * D_CNT;
            out[mb + lane] = mv;
        }
    }
}

// ---------------- fallback atomic path (ws too small) ----------------

__global__ void zero_slot1_k(float* __restrict__ out) {
    int t = blockIdx.x * blockDim.x + threadIdx.x;
    if (t >= N_CNT * 16) return;
    int n = t >> 4, q = t & 15;
    long long off = (long long)n * 256 + 64 + (long long)q * 4;
    float4 z = make_float4(0.f, 0.f, 0.f, 0.f);
    *(float4*)(out + OFF_STACK + off) = z;
    *(float4*)(out + OFF_PATH  + off) = z;
}

__global__ void scatter_fb_k(const int* __restrict__ rows, const int* __restrict__ cols,
                             const float* __restrict__ vals,
                             const float* __restrict__ user_emb, const float* __restrict__ item_emb,
                             float* __restrict__ acc) {
    long long t = (long long)blockIdx.x * blockDim.x + threadIdx.x;
    int e = (int)(t >> 4);
    if (e >= NNZ_CNT) return;
    int q = (int)(t & 15);
    int r = rows[e];
    int c = cols[e];
    float v = vals[e];
    const float* src = (c < U_CNT) ? (user_emb + (long long)c * D_CNT)
                                   : (item_emb + (long long)(c - U_CNT) * D_CNT);
    float4 x = *(const float4*)(src + q * 4);
    float* dst = acc + (long long)r * 256 + q * 4;
    atomicAdd(dst + 0, v * x.x);
    atomicAdd(dst + 1, v * x.y);
    atomicAdd(dst + 2, v * x.z);
    atomicAdd(dst + 3, v * x.w);
}

__global__ void finalize_k(const float* __restrict__ user_emb,
                           const float* __restrict__ item_emb,
                           float* __restrict__ out) {
    int t = blockIdx.x * blockDim.x + threadIdx.x;
    if (t >= N_CNT * 16) return;
    int n = t >> 4, q = t & 15;
    const float* src = (n < U_CNT) ? (user_emb + (long long)n * D_CNT)
                                   : (item_emb + (long long)(n - U_CNT) * D_CNT);
    float4 e4 = *(const float4*)(src + q * 4);
    float* st = out + OFF_STACK + (long long)n * 256;
    float* pt = out + OFF_PATH  + (long long)n * 256;
    float4 a4 = *(const float4*)(st + 64 + q * 4);
    float4 r4 = *(const float4*)(pt + 64 + q * 4);
    float4 m4 = make_float4(0.25f * e4.x + 0.75f * a4.x, 0.25f * e4.y + 0.75f * a4.y,
                            0.25f * e4.z + 0.75f * a4.z, 0.25f * e4.w + 0.75f * a4.w);
    *(float4*)(st + q * 4)       = e4;
    *(float4*)(st + 128 + q * 4) = a4;
    *(float4*)(st + 192 + q * 4) = a4;
    *(float4*)(pt + q * 4)       = e4;
    *(float4*)(pt + 128 + q * 4) = r4;
    *(float4*)(pt + 192 + q * 4) = r4;
    float* md = (n < U_CNT) ? (out + (long long)n * D_CNT)
                            : (out + OFF_ITEM + (long long)(n - U_CNT) * D_CNT);
    *(float4*)(md + q * 4) = m4;
}

extern "C" void kernel_launch(void* const* d_in, const int* in_sizes, int n_in,
                              void* d_out, int out_size, void* d_ws, size_t ws_size,
                              hipStream_t stream) {
    const float* user_emb  = (const float*)d_in[0];
    const float* item_emb  = (const float*)d_in[1];
    const int*   adj_rows  = (const int*)d_in[2];
    const int*   adj_cols  = (const int*)d_in[3];
    const float* adj_vals  = (const float*)d_in[4];
    const int*   radj_rows = (const int*)d_in[5];
    const int*   radj_cols = (const int*)d_in[6];
    const float* radj_vals = (const float*)d_in[7];
    float* out = (float*)d_out;
    const int BLK = 256;

    // ws layout (ints): cnt[2*NBUK], off[2*NBUK], cur[2*NBUK], then int2 ed[2*NNZ]
    size_t need = (size_t)(6 * NBUK) * 4 + (size_t)2 * NNZ_CNT * 8;
    if (ws_size >= need) {
        int* cnt = (int*)d_ws;
        int* off = cnt + 2 * NBUK;
        int* cur = off + 2 * NBUK;
        int2* ed = (int2*)(cur + 2 * NBUK);

        bzero_k<<<(2 * NBUK + BLK - 1) / BLK, BLK, 0, stream>>>(cnt);
        bhist_k<<<dim3(NBLD, 2), 256, 0, stream>>>(adj_rows, radj_rows, cnt);
        bscan_k<<<2, 1024, 0, stream>>>(cnt, off, cur);
        bscat_k<<<dim3(NBLD, 2), 256, 0, stream>>>(adj_rows, adj_cols, adj_vals,
                                                   radj_rows, radj_cols, radj_vals,
                                                   cur, ed);
        bspmm_k<<<dim3(NBUK, 2), 256, 0, stream>>>(off, cnt, ed, user_emb, item_emb, out);
    } else {
        int zgrid = (N_CNT * 16 + BLK - 1) / BLK;
        int sgrid = (int)(((long long)NNZ_CNT * 16 + BLK - 1) / BLK);
        zero_slot1_k<<<zgrid, BLK, 0, stream>>>(out);
        scatter_fb_k<<<sgrid, BLK, 0, stream>>>(adj_rows, adj_cols, adj_vals,
                                                user_emb, item_emb, out + OFF_STACK + 64);
        scatter_fb_k<<<sgrid, BLK, 0, stream>>>(radj_rows, radj_cols, radj_vals,
                                                user_emb, item_emb, out + OFF_PATH + 64);
        finalize_k<<<zgrid, BLK, 0, stream>>>(user_emb, item_emb, out);
    }
}